// Round 3
// baseline (2046.259 us; speedup 1.0000x reference)
//
#include <hip/hip_runtime.h>
#include <math.h>

// CASCO attention, f32-exact baseline.
// B=4, N=2048, D=768, H=12, hd=64, top_k=512.
// Pipeline:
//   1) q/k/v = X @ W^T + b   (head-split layout [B,H,N,64])
//   2) two-sweep streaming attention per (b,h,64-query tile):
//        sweep1: softmax denominators (no max-subtract: |s| < ~7, exp safe)
//        sweep2: p = exp(s)/l, ctx += p @ V, deterministic per-key column sums
//   3) deterministic f64 reduction of column partials -> mean_attn [B,N]
//   4) per-batch bitonic top-512 (f64, value desc / index asc tie-break)
//   5) gather select_value rows; 6) out = ctx @ Wo^T + bo

#define B_ 4
#define N_ 2048
#define D_ 768
#define H_ 12
#define HD_ 64
#define TOPK_ 512
#define NQT_ (N_ / 64)       // 32 query tiles per (b,h)
#define NPART_ (H_ * NQT_)   // 384 column-sum partials per (b, key)

// ---------------- GEMM: Y = X @ W^T + bias ----------------
// X:[M=8192,768], W:[768,768] row-major (torch Linear weight layout).
// HEADSPLIT: write Y to [B,H,N,64] instead of [M,768].
template <bool HEADSPLIT>
__global__ __launch_bounds__(256) void gemm_xt_kernel(
    const float* __restrict__ X, const float* __restrict__ W,
    const float* __restrict__ bias, float* __restrict__ Y) {
  __shared__ float Xs[64][36];  // pad 36: 2-way-max bank aliasing (free)
  __shared__ float Ws[64][36];
  const int t = threadIdx.x;
  const int tx = t & 15, ty = t >> 4;
  const int row0 = blockIdx.y * 64;
  const int col0 = blockIdx.x * 64;
  float acc[4][4] = {};
  for (int k0 = 0; k0 < D_; k0 += 32) {
    __syncthreads();
#pragma unroll
    for (int i = 0; i < 2; ++i) {  // 512 float4 = 64 rows x 8
      int e4 = t + i * 256;
      int r = e4 >> 3, c = (e4 & 7) * 4;
      float4 vx = *(const float4*)(X + (size_t)(row0 + r) * D_ + k0 + c);
      float4 vw = *(const float4*)(W + (size_t)(col0 + r) * D_ + k0 + c);
      *(float4*)&Xs[r][c] = vx;
      *(float4*)&Ws[r][c] = vw;
    }
    __syncthreads();
#pragma unroll 8
    for (int kk = 0; kk < 32; ++kk) {
      float a[4], b[4];
#pragma unroll
      for (int i = 0; i < 4; ++i) a[i] = Xs[ty + 16 * i][kk];
#pragma unroll
      for (int j = 0; j < 4; ++j) b[j] = Ws[tx + 16 * j][kk];
#pragma unroll
      for (int i = 0; i < 4; ++i)
#pragma unroll
        for (int j = 0; j < 4; ++j) acc[i][j] += a[i] * b[j];
    }
  }
#pragma unroll
  for (int i = 0; i < 4; ++i) {
    int r = row0 + ty + 16 * i;
#pragma unroll
    for (int j = 0; j < 4; ++j) {
      int c = col0 + tx + 16 * j;
      float v = acc[i][j] + bias[c];
      if (HEADSPLIT) {
        int bb = r >> 11, n = r & (N_ - 1);
        int hh = c >> 6, d = c & 63;
        Y[(((size_t)(bb * H_ + hh)) * N_ + n) * HD_ + d] = v;
      } else {
        Y[(size_t)r * D_ + c] = v;
      }
    }
  }
}

// ---------------- attention: two-sweep streaming softmax ----------------
__global__ __launch_bounds__(256) void attn_kernel(
    const float* __restrict__ q_s, const float* __restrict__ k_s,
    const float* __restrict__ v_s, float* __restrict__ ctx,
    float* __restrict__ colpart) {
  __shared__ float Qs[64][68];  // pad 68 keeps float4 alignment + low conflicts
  __shared__ float Ks[64][68];
  __shared__ float Vs[64][68];
  __shared__ float Ps[64][68];
  __shared__ float red[64][16];
  __shared__ float invL[64];
  const int t = threadIdx.x, tx = t & 15, ty = t >> 4;
  const int qt = blockIdx.x, h = blockIdx.y, b = blockIdx.z;
  const float* Qp = q_s + (((size_t)(b * H_ + h)) * N_ + qt * 64) * HD_;
  const float* Kp = k_s + ((size_t)(b * H_ + h)) * N_ * HD_;
  const float* Vp = v_s + ((size_t)(b * H_ + h)) * N_ * HD_;

#pragma unroll
  for (int i = 0; i < 4; ++i) {  // 1024 float4 = 64 rows x 16
    int e4 = t + i * 256;
    int r = e4 >> 4, c = (e4 & 15) * 4;
    *(float4*)&Qs[r][c] = *(const float4*)(Qp + r * HD_ + c);
  }

  // sweep 1: l[q] = sum_k exp(s/8)
  float le[4] = {0.f, 0.f, 0.f, 0.f};
  for (int step = 0; step < N_ / 64; ++step) {
    __syncthreads();
#pragma unroll
    for (int i = 0; i < 4; ++i) {
      int e4 = t + i * 256;
      int r = e4 >> 4, c = (e4 & 15) * 4;
      *(float4*)&Ks[r][c] = *(const float4*)(Kp + (size_t)(step * 64 + r) * HD_ + c);
    }
    __syncthreads();
    float s[4][4] = {};
#pragma unroll 8
    for (int kk = 0; kk < 64; ++kk) {
      float a[4], bb[4];
#pragma unroll
      for (int i = 0; i < 4; ++i) a[i] = Qs[ty + 16 * i][kk];
#pragma unroll
      for (int j = 0; j < 4; ++j) bb[j] = Ks[tx + 16 * j][kk];
#pragma unroll
      for (int i = 0; i < 4; ++i)
#pragma unroll
        for (int j = 0; j < 4; ++j) s[i][j] += a[i] * bb[j];
    }
#pragma unroll
    for (int i = 0; i < 4; ++i)
#pragma unroll
      for (int j = 0; j < 4; ++j) le[i] += expf(s[i][j] * 0.125f);
  }
  __syncthreads();
#pragma unroll
  for (int i = 0; i < 4; ++i) red[ty + 16 * i][tx] = le[i];
  __syncthreads();
  if (t < 64) {
    float l = 0.f;
    for (int x = 0; x < 16; ++x) l += red[t][x];  // fixed order: deterministic
    invL[t] = 1.0f / l;
  }

  // sweep 2: p = exp(s/8)*invL; ctx += p @ V; column sums per key
  float cacc[4][4] = {};
  for (int step = 0; step < N_ / 64; ++step) {
    __syncthreads();
#pragma unroll
    for (int i = 0; i < 4; ++i) {
      int e4 = t + i * 256;
      int r = e4 >> 4, c = (e4 & 15) * 4;
      *(float4*)&Ks[r][c] = *(const float4*)(Kp + (size_t)(step * 64 + r) * HD_ + c);
      *(float4*)&Vs[r][c] = *(const float4*)(Vp + (size_t)(step * 64 + r) * HD_ + c);
    }
    __syncthreads();
    float s[4][4] = {};
#pragma unroll 8
    for (int kk = 0; kk < 64; ++kk) {
      float a[4], bb[4];
#pragma unroll
      for (int i = 0; i < 4; ++i) a[i] = Qs[ty + 16 * i][kk];
#pragma unroll
      for (int j = 0; j < 4; ++j) bb[j] = Ks[tx + 16 * j][kk];
#pragma unroll
      for (int i = 0; i < 4; ++i)
#pragma unroll
        for (int j = 0; j < 4; ++j) s[i][j] += a[i] * bb[j];
    }
    float p[4][4];
#pragma unroll
    for (int i = 0; i < 4; ++i)
#pragma unroll
      for (int j = 0; j < 4; ++j)
        p[i][j] = expf(s[i][j] * 0.125f) * invL[ty + 16 * i];
#pragma unroll
    for (int i = 0; i < 4; ++i)
#pragma unroll
      for (int j = 0; j < 4; ++j) Ps[ty + 16 * i][tx + 16 * j] = p[i][j];
#pragma unroll
    for (int j = 0; j < 4; ++j)
      red[tx + 16 * j][ty] = p[0][j] + p[1][j] + p[2][j] + p[3][j];
    __syncthreads();
#pragma unroll 8
    for (int kk = 0; kk < 64; ++kk) {
      float a[4], bb[4];
#pragma unroll
      for (int i = 0; i < 4; ++i) a[i] = Ps[ty + 16 * i][kk];
#pragma unroll
      for (int j = 0; j < 4; ++j) bb[j] = Vs[kk][tx + 16 * j];
#pragma unroll
      for (int i = 0; i < 4; ++i)
#pragma unroll
        for (int j = 0; j < 4; ++j) cacc[i][j] += a[i] * bb[j];
    }
    if (t < 64) {
      float ssum = 0.f;
      for (int y = 0; y < 16; ++y) ssum += red[t][y];  // deterministic
      colpart[(((size_t)b * H_ + h) * NQT_ + qt) * N_ + step * 64 + t] = ssum;
    }
  }
#pragma unroll
  for (int i = 0; i < 4; ++i)
#pragma unroll
    for (int j = 0; j < 4; ++j)
      ctx[((size_t)b * N_ + qt * 64 + ty + 16 * i) * D_ + h * HD_ + tx + 16 * j] =
          cacc[i][j];
}

// ---------------- deterministic f64 reduce of column partials ----------------
__global__ __launch_bounds__(256) void colreduce_kernel(
    const float* __restrict__ colpart, double* __restrict__ meanattn) {
  int i = blockIdx.x * 256 + threadIdx.x;  // 0..B*N-1
  int b = i >> 11, k = i & (N_ - 1);
  const float* p = colpart + (size_t)b * NPART_ * N_ + k;
  double s = 0.0;
  for (int j = 0; j < NPART_; ++j) s += (double)p[(size_t)j * N_];
  meanattn[i] = s / (double)(H_ * N_);
}

// ---------------- per-batch bitonic top-512 ----------------
__global__ __launch_bounds__(1024) void topk_kernel(
    const double* __restrict__ meanattn, int* __restrict__ kidx) {
  __shared__ double val[N_];
  __shared__ int idx[N_];
  const int b = blockIdx.x, t = threadIdx.x;
  for (int i = t; i < N_; i += 1024) {
    val[i] = meanattn[b * N_ + i];
    idx[i] = i;
  }
  __syncthreads();
  for (int k = 2; k <= N_; k <<= 1) {
    for (int j = k >> 1; j > 0; j >>= 1) {
      int lo = t & (j - 1);
      int i1 = ((t - lo) << 1) + lo;
      int i2 = i1 + j;
      bool dir = ((i1 & k) == 0);  // true -> descending segment
      double v1 = val[i1], v2 = val[i2];
      int x1 = idx[i1], x2 = idx[i2];
      // "before" in final order: larger value first; tie -> smaller index first
      bool before = (v1 > v2) || (v1 == v2 && x1 < x2);
      if (before != dir) {
        val[i1] = v2; val[i2] = v1;
        idx[i1] = x2; idx[i2] = x1;
      }
      __syncthreads();
    }
  }
  for (int i = t; i < TOPK_; i += 1024) kidx[b * TOPK_ + i] = idx[i];
}

// ---------------- gather select_value ----------------
__global__ __launch_bounds__(256) void gather_kernel(
    const float* __restrict__ value, const int* __restrict__ kidx,
    float* __restrict__ sv) {
  size_t i = (size_t)blockIdx.x * 256 + threadIdx.x;  // < B*TOPK*D
  int d = (int)(i % D_);
  int j = (int)((i / D_) % TOPK_);
  int b = (int)(i / ((size_t)D_ * TOPK_));
  sv[i] = value[((size_t)b * N_ + kidx[b * TOPK_ + j]) * D_ + d];
}

extern "C" void kernel_launch(void* const* d_in, const int* in_sizes, int n_in,
                              void* d_out, int out_size, void* d_ws,
                              size_t ws_size, hipStream_t stream) {
  const float* query = (const float*)d_in[0];
  const float* key = (const float*)d_in[1];
  const float* value = (const float*)d_in[2];
  const float* Wq = (const float*)d_in[3];
  const float* bq = (const float*)d_in[4];
  const float* Wk = (const float*)d_in[5];
  const float* bk = (const float*)d_in[6];
  const float* Wv = (const float*)d_in[7];
  const float* bv = (const float*)d_in[8];
  const float* Wo = (const float*)d_in[9];
  const float* bo = (const float*)d_in[10];
  // d_in[11] = top_k (known 512, hardcoded)

  float* ws = (float*)d_ws;
  const size_t SZ_BND = (size_t)B_ * N_ * D_;  // 6291456 floats
  float* qs = ws;
  float* ks = qs + SZ_BND;
  float* vs = ks + SZ_BND;
  float* ctxb = vs + SZ_BND;
  float* colp = ctxb + SZ_BND;                              // B*NPART*N floats
  double* meanattn = (double*)(colp + (size_t)B_ * NPART_ * N_);  // 8B-aligned
  int* kidx = (int*)(meanattn + (size_t)B_ * N_);
  // total ws: ~113.4 MB

  float* out_main = (float*)d_out;
  float* out_sel = out_main + SZ_BND;

  dim3 gemmGrid(D_ / 64, (B_ * N_) / 64);  // (12,128)
  gemm_xt_kernel<true><<<gemmGrid, 256, 0, stream>>>(query, Wq, bq, qs);
  gemm_xt_kernel<true><<<gemmGrid, 256, 0, stream>>>(key, Wk, bk, ks);
  gemm_xt_kernel<true><<<gemmGrid, 256, 0, stream>>>(value, Wv, bv, vs);

  attn_kernel<<<dim3(NQT_, H_, B_), 256, 0, stream>>>(qs, ks, vs, ctxb, colp);

  colreduce_kernel<<<(B_ * N_) / 256, 256, 0, stream>>>(colp, meanattn);
  topk_kernel<<<B_, 1024, 0, stream>>>(meanattn, kidx);
  gather_kernel<<<(int)(((size_t)B_ * TOPK_ * D_) / 256), 256, 0, stream>>>(
      value, kidx, out_sel);

  gemm_xt_kernel<false><<<gemmGrid, 256, 0, stream>>>(ctxb, Wo, bo, out_main);
}

// Round 6
// 1178.906 us; speedup vs baseline: 1.7357x; 1.7357x over previous
//
#include <hip/hip_runtime.h>
#include <math.h>

// CASCO attention. B=4, N=2048, D=768, H=12, hd=64, top_k=512.
// Round 6: K 3-level split (hi+lo+lo2, eps_K ~ 2^-27) for the score path.
// Rationale: select_value is rank-ordered, so tolerance = MIN adjacent
// mean_attn gap (~4e-11); 2-level K's per-key systematic (~4e-10) flipped
// ranks deterministically (identical absmax in rounds 4&5). Q stays 2-level
// (per-query errors are 1/sqrt(24576) noise-suppressed).
//  - S = qhi*khi + qhi*klo + qlo*khi + qhi*klo2   (4 MFMAs / 16-d chunk)
//  - PV: single bf16 P and V (colsums from f32 p before rounding)
//  - colsum: in-wave shuffle reduce (certified == Pt-tile version in r4/r5)

#define B_ 4
#define N_ 2048
#define D_ 768
#define H_ 12
#define HD_ 64
#define TOPK_ 512
#define NQT_ (N_ / 64)       // 32 query tiles per (b,h)
#define NPART_ (H_ * NQT_)   // 384 column-sum partials per (b, key)

typedef __attribute__((ext_vector_type(8))) short short8;    // 8 bf16 = 4 VGPR
typedef __attribute__((ext_vector_type(16))) float f32x16;   // 32x32 accum

static __device__ __forceinline__ unsigned short f2bf(float x) {
  unsigned u = __float_as_uint(x);
  u += 0x7fffu + ((u >> 16) & 1u);   // RNE; finite normal inputs
  return (unsigned short)(u >> 16);
}
static __device__ __forceinline__ float bf2f(unsigned short h) {
  return __uint_as_float(((unsigned)h) << 16);
}

// ---------------- GEMM: Y = X @ W^T + bias ----------------
// MODE 0: f32 out [M][768]. MODE 1: head-split bf16 hi+lo. MODE 2: hi only.
// MODE 3: head-split bf16 hi+lo+lo2 (3-level residual split, exact in f32).
template <int MODE>
__global__ __launch_bounds__(256) void gemm_xt_kernel(
    const float* __restrict__ X, const float* __restrict__ W,
    const float* __restrict__ bias, float* __restrict__ Yf,
    unsigned short* __restrict__ Yhi, unsigned short* __restrict__ Ylo,
    unsigned short* __restrict__ Ylo2) {
  __shared__ __attribute__((aligned(16))) float Xs[64][36];
  __shared__ __attribute__((aligned(16))) float Ws[64][36];
  const int t = threadIdx.x;
  const int tx = t & 15, ty = t >> 4;
  const int row0 = blockIdx.y * 64;
  const int col0 = blockIdx.x * 64;
  float acc[4][4] = {};
  for (int k0 = 0; k0 < D_; k0 += 32) {
    __syncthreads();
#pragma unroll
    for (int i = 0; i < 2; ++i) {
      int e4 = t + i * 256;
      int r = e4 >> 3, c = (e4 & 7) * 4;
      float4 vx = *(const float4*)(X + (size_t)(row0 + r) * D_ + k0 + c);
      float4 vw = *(const float4*)(W + (size_t)(col0 + r) * D_ + k0 + c);
      *(float4*)&Xs[r][c] = vx;
      *(float4*)&Ws[r][c] = vw;
    }
    __syncthreads();
#pragma unroll 8
    for (int kk = 0; kk < 32; ++kk) {
      float a[4], b[4];
#pragma unroll
      for (int i = 0; i < 4; ++i) a[i] = Xs[ty + 16 * i][kk];
#pragma unroll
      for (int j = 0; j < 4; ++j) b[j] = Ws[tx + 16 * j][kk];
#pragma unroll
      for (int i = 0; i < 4; ++i)
#pragma unroll
        for (int j = 0; j < 4; ++j) acc[i][j] += a[i] * b[j];
    }
  }
#pragma unroll
  for (int i = 0; i < 4; ++i) {
    int r = row0 + ty + 16 * i;
#pragma unroll
    for (int j = 0; j < 4; ++j) {
      int c = col0 + tx + 16 * j;
      float v = acc[i][j] + bias[c];
      if (MODE == 0) {
        Yf[(size_t)r * D_ + c] = v;
      } else {
        int bb = r >> 11, n = r & (N_ - 1);
        int hh = c >> 6, d = c & 63;
        size_t o = (((size_t)(bb * H_ + hh)) * N_ + n) * HD_ + d;
        unsigned short hv = f2bf(v);
        Yhi[o] = hv;
        if (MODE >= 1 && MODE != 2) {
          float r1 = v - bf2f(hv);          // exact (Sterbenz)
          unsigned short lv = f2bf(r1);
          Ylo[o] = lv;
          if (MODE == 3) {
            float r2 = r1 - bf2f(lv);       // exact
            Ylo2[o] = f2bf(r2);
          }
        }
      }
    }
  }
}

// ---------------- V transpose: [bh][n][64] -> [bh][64][n] (bf16) -------------
__global__ __launch_bounds__(256) void vtrans_kernel(
    const unsigned short* __restrict__ vhi, unsigned short* __restrict__ vt) {
  __shared__ __attribute__((aligned(16))) unsigned short T[64][72];
  const int t = threadIdx.x;
  const int n0 = blockIdx.x * 64, bh = blockIdx.y;
  const unsigned short* src = vhi + ((size_t)bh * N_ + n0) * HD_;
#pragma unroll
  for (int i = 0; i < 2; ++i) {
    int c = t + i * 256;
    int r = c >> 3, g = c & 7;
    *(uint4*)&T[r][g * 8] = *(const uint4*)(src + (size_t)r * HD_ + g * 8);
  }
  __syncthreads();
#pragma unroll
  for (int i = 0; i < 2; ++i) {
    int c = t + i * 256;
    int d = c >> 3, g = c & 7;
    unsigned short tmp[8];
#pragma unroll
    for (int j = 0; j < 8; ++j) tmp[j] = T[g * 8 + j][d];
    *(uint4*)(vt + ((size_t)bh * HD_ + d) * N_ + n0 + g * 8) = *(uint4*)tmp;
  }
}

// ---------------- MFMA attention ----------------
// Block: 256 thr = 4 waves; 64 queries. Wave w: qh=w>>1, kh=w&1 (QK), dh=w&1 (PV).
// C/D 32x32: col=lane&31, row=(reg&3)+8*(reg>>2)+4*(lane>>5).
// A: row=lane&31, k=(lane>>5)*8+j.  B: col=lane&31, k=(lane>>5)*8+j.
__global__ __launch_bounds__(256) void attn_mfma_kernel(
    const unsigned short* __restrict__ qhi, const unsigned short* __restrict__ qlo,
    const unsigned short* __restrict__ khi, const unsigned short* __restrict__ klo,
    const unsigned short* __restrict__ klo2, const unsigned short* __restrict__ vt,
    float* __restrict__ ctx, float* __restrict__ colpart) {
  __shared__ __attribute__((aligned(16))) unsigned short Khi[64 * 64];
  __shared__ __attribute__((aligned(16))) unsigned short Klo[64 * 64];
  __shared__ __attribute__((aligned(16))) unsigned short Kl2[64 * 64];
  __shared__ __attribute__((aligned(16))) unsigned short Vs[64 * 64];
  __shared__ __attribute__((aligned(16))) unsigned short Ps[64 * 64];
  __shared__ __attribute__((aligned(16))) float lsum[64][2];
  __shared__ __attribute__((aligned(16))) float invl[64];
  __shared__ __attribute__((aligned(16))) float red[4][64];

  const int t = threadIdx.x;
  const int w = t >> 6, l = t & 63, lh = l >> 5, l31 = l & 31;
  const int qh = w >> 1, kh = w & 1, dh = w & 1;
  const int qt = blockIdx.x, h = blockIdx.y, b = blockIdx.z;
  const int bh = b * H_ + h;
  const size_t kbase = (size_t)bh * N_ * HD_;

  short8 qAhi[4], qAlo[4];
  {
    const size_t qo = kbase + (size_t)(qt * 64 + qh * 32 + l31) * HD_ + lh * 8;
#pragma unroll
    for (int dc = 0; dc < 4; ++dc) {
      qAhi[dc] = *(const short8*)(qhi + qo + dc * 16);
      qAlo[dc] = *(const short8*)(qlo + qo + dc * 16);
    }
  }

  auto stageK = [&](int s) {
#pragma unroll
    for (int i = 0; i < 2; ++i) {
      int c = t + i * 256, r = c >> 3, g = c & 7, g2 = g ^ (r & 7);
      *(uint4*)&Khi[r * 64 + g2 * 8] =
          *(const uint4*)(khi + kbase + (size_t)(s * 64 + r) * HD_ + g * 8);
      *(uint4*)&Klo[r * 64 + g2 * 8] =
          *(const uint4*)(klo + kbase + (size_t)(s * 64 + r) * HD_ + g * 8);
      *(uint4*)&Kl2[r * 64 + g2 * 8] =
          *(const uint4*)(klo2 + kbase + (size_t)(s * 64 + r) * HD_ + g * 8);
    }
  };
  auto stageV = [&](int s) {
#pragma unroll
    for (int i = 0; i < 2; ++i) {
      int c = t + i * 256, r = c >> 3, g = c & 7, g2 = g ^ (r & 7);
      *(uint4*)&Vs[r * 64 + g2 * 8] =
          *(const uint4*)(vt + ((size_t)bh * HD_ + r) * N_ + s * 64 + g * 8);
    }
  };

  const int krow = kh * 32 + l31;
  const int swz = l31 & 7;

  // 4-term split: qhi*khi + qhi*klo + qlo*khi + qhi*klo2  (K complete to 2^-27)
  auto computeS = [&]() -> f32x16 {
    f32x16 S = {};
#pragma unroll
    for (int dc = 0; dc < 4; ++dc) {
      int c8 = (dc * 2 + lh) ^ swz;
      short8 bh_ = *(const short8*)&Khi[krow * 64 + c8 * 8];
      short8 bl_ = *(const short8*)&Klo[krow * 64 + c8 * 8];
      short8 b2_ = *(const short8*)&Kl2[krow * 64 + c8 * 8];
      S = __builtin_amdgcn_mfma_f32_32x32x16_bf16(qAhi[dc], bh_, S, 0, 0, 0);
      S = __builtin_amdgcn_mfma_f32_32x32x16_bf16(qAhi[dc], bl_, S, 0, 0, 0);
      S = __builtin_amdgcn_mfma_f32_32x32x16_bf16(qAlo[dc], bh_, S, 0, 0, 0);
      S = __builtin_amdgcn_mfma_f32_32x32x16_bf16(qAhi[dc], b2_, S, 0, 0, 0);
    }
    return S;
  };

  // exp(s_raw/8) = exp2(s_raw * 0.125 * log2(e))
  const float C2 = 0.18033688f;

  // ---- sweep 1: l[q] = sum_k exp ----
  float le[16];
#pragma unroll
  for (int r = 0; r < 16; ++r) le[r] = 0.f;
  for (int s = 0; s < N_ / 64; ++s) {
    __syncthreads();
    stageK(s);
    __syncthreads();
    f32x16 S = computeS();
#pragma unroll
    for (int r = 0; r < 16; ++r) le[r] += exp2f(S[r] * C2);
  }
#pragma unroll
  for (int r = 0; r < 16; ++r) {
#pragma unroll
    for (int m = 1; m < 32; m <<= 1) le[r] += __shfl_xor(le[r], m);
  }
#pragma unroll
  for (int r = 0; r < 16; ++r) {
    if (l31 == r) lsum[qh * 32 + (r & 3) + 8 * (r >> 2) + 4 * lh][kh] = le[r];
  }
  __syncthreads();
  if (t < 64) invl[t] = 1.0f / (lsum[t][0] + lsum[t][1]);
  __syncthreads();
  float ivr[16];
#pragma unroll
  for (int r = 0; r < 16; ++r)
    ivr[r] = invl[qh * 32 + (r & 3) + 8 * (r >> 2) + 4 * lh];  // scalar reads

  // ---- sweep 2: p, colsums (shuffle), PV ----
  f32x16 ctxa = {};
  const int qrow = qh * 32 + l31;
  for (int s = 0; s < N_ / 64; ++s) {
    __syncthreads();
    stageK(s);
    stageV(s);
    __syncthreads();
    f32x16 S = computeS();
    float p[16];
#pragma unroll
    for (int r = 0; r < 16; ++r) p[r] = exp2f(S[r] * C2) * ivr[r];
    // column sums: lane holds key col l31 for 16 rows; sum rows, fold lh halves
    float cs = 0.f;
#pragma unroll
    for (int r = 0; r < 16; ++r) cs += p[r];
    cs += __shfl_xor(cs, 32);
    if (lh == 0) red[w][kh * 32 + l31] = cs;
    // P -> bf16 LDS (pack col-pairs via lane-xor-1; even lanes write b32)
#pragma unroll
    for (int r = 0; r < 16; ++r) {
      float pn = __shfl_xor(p[r], 1);
      if ((l & 1) == 0) {
        int row = qh * 32 + (r & 3) + 8 * (r >> 2) + 4 * lh;
        int c = kh * 32 + l31;
        unsigned up = (unsigned)f2bf(p[r]) | ((unsigned)f2bf(pn) << 16);
        *(unsigned*)&Ps[row * 64 + (((c >> 3) ^ (row & 7)) << 3) + (c & 7)] = up;
      }
    }
    __syncthreads();
    if (t < 64) {
      float cp = red[t >> 5][t] + red[2 + (t >> 5)][t];  // qh=0 + qh=1 halves
      colpart[((size_t)bh * NQT_ + qt) * N_ + s * 64 + t] = cp;
    }
    // PV: ctx[qh-rows][dh-cols] += P * V
    const int drow = dh * 32 + l31;
#pragma unroll
    for (int kc = 0; kc < 4; ++kc) {
      int c8 = (kc * 2 + lh) ^ swz;
      short8 pa = *(const short8*)&Ps[qrow * 64 + c8 * 8];
      short8 vb = *(const short8*)&Vs[drow * 64 + c8 * 8];
      ctxa = __builtin_amdgcn_mfma_f32_32x32x16_bf16(pa, vb, ctxa, 0, 0, 0);
    }
  }
#pragma unroll
  for (int r = 0; r < 16; ++r) {
    int q = qt * 64 + qh * 32 + (r & 3) + 8 * (r >> 2) + 4 * lh;
    ctx[((size_t)b * N_ + q) * D_ + h * HD_ + dh * 32 + l31] = ctxa[r];
  }
}

// ---------------- deterministic f64 reduce of column partials ----------------
__global__ __launch_bounds__(256) void colreduce_kernel(
    const float* __restrict__ colpart, double* __restrict__ meanattn) {
  int i = blockIdx.x * 256 + threadIdx.x;
  int b = i >> 11, k = i & (N_ - 1);
  const float* p = colpart + (size_t)b * NPART_ * N_ + k;
  double s = 0.0;
  for (int j = 0; j < NPART_; ++j) s += (double)p[(size_t)j * N_];
  meanattn[i] = s / (double)(H_ * N_);
}

// ---------------- per-batch bitonic top-512 ----------------
__global__ __launch_bounds__(1024) void topk_kernel(
    const double* __restrict__ meanattn, int* __restrict__ kidx) {
  __shared__ double val[N_];
  __shared__ int idx[N_];
  const int b = blockIdx.x, t = threadIdx.x;
  for (int i = t; i < N_; i += 1024) {
    val[i] = meanattn[b * N_ + i];
    idx[i] = i;
  }
  __syncthreads();
  for (int k = 2; k <= N_; k <<= 1) {
    for (int j = k >> 1; j > 0; j >>= 1) {
      int lo = t & (j - 1);
      int i1 = ((t - lo) << 1) + lo;
      int i2 = i1 + j;
      bool dir = ((i1 & k) == 0);
      double v1 = val[i1], v2 = val[i2];
      int x1 = idx[i1], x2 = idx[i2];
      bool before = (v1 > v2) || (v1 == v2 && x1 < x2);
      if (before != dir) {
        val[i1] = v2; val[i2] = v1;
        idx[i1] = x2; idx[i2] = x1;
      }
      __syncthreads();
    }
  }
  for (int i = t; i < TOPK_; i += 1024) kidx[b * TOPK_ + i] = idx[i];
}

// ---------------- gather select_value ----------------
__global__ __launch_bounds__(256) void gather_kernel(
    const float* __restrict__ value, const int* __restrict__ kidx,
    float* __restrict__ sv) {
  size_t i = (size_t)blockIdx.x * 256 + threadIdx.x;
  int d = (int)(i % D_);
  int j = (int)((i / D_) % TOPK_);
  int b = (int)(i / ((size_t)D_ * TOPK_));
  sv[i] = value[((size_t)b * N_ + kidx[b * TOPK_ + j]) * D_ + d];
}

extern "C" void kernel_launch(void* const* d_in, const int* in_sizes, int n_in,
                              void* d_out, int out_size, void* d_ws,
                              size_t ws_size, hipStream_t stream) {
  const float* query = (const float*)d_in[0];
  const float* key = (const float*)d_in[1];
  const float* value = (const float*)d_in[2];
  const float* Wq = (const float*)d_in[3];
  const float* bq = (const float*)d_in[4];
  const float* Wk = (const float*)d_in[5];
  const float* bk = (const float*)d_in[6];
  const float* Wv = (const float*)d_in[7];
  const float* bv = (const float*)d_in[8];
  const float* Wo = (const float*)d_in[9];
  const float* bo = (const float*)d_in[10];

  const size_t NE = (size_t)B_ * H_ * N_ * HD_;  // 6291456
  unsigned short* qhi_ = (unsigned short*)d_ws;
  unsigned short* qlo_ = qhi_ + NE;
  unsigned short* khi_ = qlo_ + NE;
  unsigned short* klo_ = khi_ + NE;
  unsigned short* vhi_ = klo_ + NE;   // dead after vtrans; reused as klo2
  unsigned short* klo2_ = vhi_;       // written by gemm-K AFTER vtrans
  unsigned short* vt_ = vhi_ + NE;
  float* ctxb = (float*)(vt_ + NE);
  float* colp = ctxb + (size_t)B_ * N_ * D_;
  double* meanattn = (double*)(colp + (size_t)B_ * NPART_ * N_);
  int* kidx = (int*)(meanattn + (size_t)B_ * N_);
  // total ws ~113.3 MB (unchanged from round 4/5)

  float* out_main = (float*)d_out;
  float* out_sel = out_main + (size_t)B_ * N_ * D_;

  dim3 gemmGrid(D_ / 64, (B_ * N_) / 64);  // (12,128)
  gemm_xt_kernel<1><<<gemmGrid, 256, 0, stream>>>(query, Wq, bq, nullptr, qhi_, qlo_, nullptr);
  gemm_xt_kernel<2><<<gemmGrid, 256, 0, stream>>>(value, Wv, bv, nullptr, vhi_, nullptr, nullptr);
  vtrans_kernel<<<dim3(N_ / 64, B_ * H_), 256, 0, stream>>>(vhi_, vt_);
  // gemm-K after vtrans: klo2 overwrites vhi's buffer (vhi now dead)
  gemm_xt_kernel<3><<<gemmGrid, 256, 0, stream>>>(key, Wk, bk, nullptr, khi_, klo_, klo2_);

  attn_mfma_kernel<<<dim3(NQT_, H_, B_), 256, 0, stream>>>(
      qhi_, qlo_, khi_, klo_, klo2_, vt_, ctxb, colp);

  colreduce_kernel<<<(B_ * N_) / 256, 256, 0, stream>>>(colp, meanattn);
  topk_kernel<<<B_, 1024, 0, stream>>>(meanattn, kidx);
  gather_kernel<<<(int)(((size_t)B_ * TOPK_ * D_) / 256), 256, 0, stream>>>(
      value, kidx, out_sel);

  gemm_xt_kernel<0><<<gemmGrid, 256, 0, stream>>>(ctxb, Wo, bo, out_main, nullptr, nullptr, nullptr);
}